// Round 1
// baseline (37379.276 us; speedup 1.0000x reference)
//
#include <hip/hip_runtime.h>
#include <stdint.h>

// LSTM_29042568856007: B=64, T=4096, D=256, H=256.
// One workgroup per batch element (64 WGs, fully independent -> no grid sync).
// Weights pre-packed to bf16 pairs in d_ws, transposed to [k][r] (r contiguous)
// for coalesced loads. fp32 accumulate; bf16 unpacked with bit ops (free-ish).

#define LSTM_B 64
#define LSTM_T 4096
#define LSTM_D 256
#define LSTM_H 256
#define LSTM_G 1024  // 4*H

// ws layout: uint4 Wp[64][1024]   (k4, r), 1 MiB total
//   k4 in [0,32): x-part, covers k = k4*8 .. k4*8+7 of W_ih row r
//   k4 in [32,64): h-part, same for W_hh

static __device__ __forceinline__ uint32_t f32_to_bf16_rne(float f) {
    uint32_t u = __float_as_uint(f);
    uint32_t rounding = 0x7fffu + ((u >> 16) & 1u);
    return (u + rounding) >> 16;
}

__global__ __launch_bounds__(256) void prep_weights(
    const float* __restrict__ W_ih, const float* __restrict__ W_hh,
    uint32_t* __restrict__ Wp)
{
    int idx = blockIdx.x * blockDim.x + threadIdx.x;  // u32 index in [0, 64*1024*4)
    if (idx >= 64 * 1024 * 4) return;
    int j  = idx & 3;            // which u32 inside the uint4
    int r  = (idx >> 2) & 1023;  // gate row
    int k4 = idx >> 12;          // 8-wide k group
    int k  = ((k4 & 31) << 3) + (j << 1);
    const float* W = (k4 < 32) ? W_ih : W_hh;
    float f0 = W[r * 256 + k];
    float f1 = W[r * 256 + k + 1];
    Wp[idx] = f32_to_bf16_rne(f0) | (f32_to_bf16_rne(f1) << 16);
}

static __device__ __forceinline__ float sigmoidf_(float x) {
    return 1.0f / (1.0f + __expf(-x));
}
static __device__ __forceinline__ float tanhf_(float x) {
    float ax = fabsf(x);
    float e  = __expf(-2.0f * ax);
    float t  = (1.0f - e) / (1.0f + e);
    return copysignf(t, x);
}

// 8 bf16 weights (uint4 w) * 8 fp32 activations (a0,a1), two accumulators for ILP
#define UNPACK_FMA8(w, a0, a1)                                         \
    acc0 = fmaf(__uint_as_float((w).x << 16),          (a0).x, acc0);  \
    acc1 = fmaf(__uint_as_float((w).x & 0xffff0000u),  (a0).y, acc1);  \
    acc0 = fmaf(__uint_as_float((w).y << 16),          (a0).z, acc0);  \
    acc1 = fmaf(__uint_as_float((w).y & 0xffff0000u),  (a0).w, acc1);  \
    acc0 = fmaf(__uint_as_float((w).z << 16),          (a1).x, acc0);  \
    acc1 = fmaf(__uint_as_float((w).z & 0xffff0000u),  (a1).y, acc1);  \
    acc0 = fmaf(__uint_as_float((w).w << 16),          (a1).z, acc0);  \
    acc1 = fmaf(__uint_as_float((w).w & 0xffff0000u),  (a1).w, acc1);

__global__ __launch_bounds__(1024) void lstm_persistent(
    const float* __restrict__ xs,   // [B, T, D]
    const float* __restrict__ bias_g, // [4H]
    const uint4* __restrict__ Wp,   // [64][1024]
    float* __restrict__ out)        // h[B,H] then c[B,H]
{
    __shared__ __align__(16) float x_s[LSTM_D];
    __shared__ __align__(16) float h_s[LSTM_H];
    __shared__ __align__(16) float g_s[LSTM_G];

    const int tid = threadIdx.x;   // gate row r = tid
    const int bb  = blockIdx.x;    // batch element

    const float bias = bias_g[tid];
    if (tid < LSTM_H) h_s[tid] = 0.0f;
    float c = 0.0f;

    const float* xrow = xs + (size_t)bb * LSTM_T * LSTM_D;
    const uint4* Wr   = Wp + tid;  // stride 1024 uint4 per k4

    for (int t = 0; t < LSTM_T; ++t) {
        // stage x_t (all threads passed the previous step's post-gate barrier,
        // so previous x_s/h_s reads are complete)
        if (tid < LSTM_D) x_s[tid] = xrow[t * LSTM_D + tid];
        __syncthreads();  // bar A: x_s & h_s visible to everyone

        float acc0 = bias, acc1 = 0.0f;
        const float4* x4 = (const float4*)x_s;
        #pragma unroll 8
        for (int k4 = 0; k4 < 32; ++k4) {
            uint4  w  = Wr[k4 << 10];
            float4 a0 = x4[2 * k4];
            float4 a1 = x4[2 * k4 + 1];
            UNPACK_FMA8(w, a0, a1)
        }
        const float4* h4 = (const float4*)h_s;
        #pragma unroll 8
        for (int k4 = 0; k4 < 32; ++k4) {
            uint4  w  = Wr[(k4 + 32) << 10];
            float4 a0 = h4[2 * k4];
            float4 a1 = h4[2 * k4 + 1];
            UNPACK_FMA8(w, a0, a1)
        }
        g_s[tid] = acc0 + acc1;
        __syncthreads();  // bar B: gates visible

        if (tid < LSTM_H) {
            float gi = g_s[tid];
            float gf = g_s[tid + 256];
            float gg = g_s[tid + 512];
            float go = g_s[tid + 768];
            c = sigmoidf_(gf) * c + sigmoidf_(gi) * tanhf_(gg);
            h_s[tid] = sigmoidf_(go) * tanhf_(c);
        }
        // next iteration's bar A orders h_s write -> dot-loop reads;
        // g_s is only rewritten after bar A, after the updaters' reads.
    }

    if (tid < LSTM_H) {
        out[bb * LSTM_H + tid]                     = h_s[tid];  // h (written by this thread)
        out[LSTM_B * LSTM_H + bb * LSTM_H + tid]   = c;         // c
    }
}

extern "C" void kernel_launch(void* const* d_in, const int* in_sizes, int n_in,
                              void* d_out, int out_size, void* d_ws, size_t ws_size,
                              hipStream_t stream) {
    const float* xs   = (const float*)d_in[0];  // [64,4096,256]
    const float* W_ih = (const float*)d_in[1];  // [1024,256]
    const float* W_hh = (const float*)d_in[2];  // [1024,256]
    const float* b    = (const float*)d_in[3];  // [1024]
    float* out = (float*)d_out;
    uint32_t* Wp = (uint32_t*)d_ws;             // 1 MiB packed bf16 weights

    // pack weights (re-run every launch: d_ws is re-poisoned by the harness)
    prep_weights<<<1024, 256, 0, stream>>>(W_ih, W_hh, Wp);
    // persistent per-batch LSTM
    lstm_persistent<<<LSTM_B, 1024, 0, stream>>>(xs, b, (const uint4*)Wp, out);
}